// Round 7
// baseline (104.294 us; speedup 1.0000x reference)
//
#include <hip/hip_runtime.h>
#include <hip/hip_bf16.h>

#define HH 256
#define WW 832
#define OHH 128
#define OWW 208
#define NCAND 240
#define MM (OHH*OWW)

typedef float v2f __attribute__((ext_vector_type(2)));

__device__ __forceinline__ int iclamp(int v, int lo, int hi) { return min(max(v, lo), hi); }
__device__ __forceinline__ int mbcnt2(unsigned lo, unsigned hi) {
    return __builtin_amdgcn_mbcnt_hi(hi, __builtin_amdgcn_mbcnt_lo(lo, 0));
}
__device__ __forceinline__ v2f sxor(v2f v, int m) {
    v2f r; r.x = __shfl_xor(v.x, m); r.y = __shfl_xor(v.y, m); return r;
}

// One wave = 2 centers: lanes 0-31 -> center A, lanes 32-63 -> center B.
// Candidate word r (r=0..7): candidate j = r*32 + (lane&31), same j for both halves.
// The radix walk is shared: one ballot per word covers both centers; per-half
// counts via popc of lo/hi 32 bits. Serial chain cost per center is halved.
__global__ void __launch_bounds__(256) sa_fused(
    const float* __restrict__ pos1, const float* __restrict__ pos2,
    const float* __restrict__ w1, const float* __restrict__ b1,
    const float* __restrict__ w2, const float* __restrict__ b2,
    const float* __restrict__ w3, const float* __restrict__ b3,
    float* __restrict__ out)
{
    // weights as channel-pair float2 for v_pk_fma_f32
    __shared__ v2f sW1p[3][4];
    __shared__ v2f sW2p[8][4];
    __shared__ v2f sW3p[8][8];
    __shared__ v2f sB1p[4], sB2p[4], sB3p[8];
    __shared__ float4 selRel[256];   // 4 waves x 2 centers x 32 rel-coords

    const int t = threadIdx.x;
    if (t < 12)              { int i = t >> 2,  op = t & 3;
        sW1p[i][op] = (v2f){w1[i*8 + 2*op], w1[i*8 + 2*op + 1]}; }
    if (t >= 16 && t < 48)   { int u = t - 16, i = u >> 2, op = u & 3;
        sW2p[i][op] = (v2f){w2[i*8 + 2*op], w2[i*8 + 2*op + 1]}; }
    if (t >= 64 && t < 128)  { int u = t - 64, i = u >> 3, op = u & 7;
        sW3p[i][op] = (v2f){w3[i*16 + 2*op], w3[i*16 + 2*op + 1]}; }
    if (t >= 128 && t < 132) { int u = t - 128; sB1p[u] = (v2f){b1[2*u], b1[2*u + 1]}; }
    if (t >= 132 && t < 136) { int u = t - 132; sB2p[u] = (v2f){b2[2*u], b2[2*u + 1]}; }
    if (t >= 136 && t < 144) { int u = t - 136; sB3p[u] = (v2f){b3[2*u], b3[2*u + 1]}; }
    __syncthreads();

    const int lane = t & 63;
    const int wid  = t >> 6;
    const int l31  = lane & 31;
    const int half = lane >> 5;                     // 0 = center A, 1 = center B
    const int m    = blockIdx.x * 8 + wid * 2 + half;   // per-lane center id
    const int b    = blockIdx.y & 1;
    const int cl   = blockIdx.y >> 1;
    const float* __restrict__ base = (cl ? pos2 : pos1) + (size_t)b * (HH * WW * 3);

    // oh = m / 208 = (m>>4)/13 via magic 5042/2^16 (exact for x<=2047)
    const int oh = (int)(((unsigned)(m >> 4) * 5042u) >> 16);
    const int ow = m - oh * OWW;
    const int h0 = oh * 2, w0 = ow * 4;

    const int cidx = (h0 * WW + w0) * 3;
    const float cx = base[cidx + 0];
    const float cy = base[cidx + 1];
    const float cz = base[cidx + 2];

    // ---- distances: word r covers candidates j = r*32 + l31 ----
    unsigned d2b[8];
    float rxv[8], ryv[8], rzv[8];
    const bool interior = ((unsigned)(oh - 3) <= 122u) && ((unsigned)(ow - 3) <= 202u);
    const bool allInt = (__ballot(interior) == ~0ull);
    if (allInt) {
        const float* wb = base + ((h0 - 6) * WW + (w0 - 10)) * 3;
        #pragma unroll
        for (int r = 0; r < 8; ++r) {
            int j = r * 32 + l31;
            if (r == 7) j = min(j, NCAND - 1);   // tail lanes: safe in-window read
            int kh = (j * 205) >> 12;            // j/20 for j < 256
            int kw = j - kh * 20;
            const float* p = wb + (kh * WW + kw) * 3;
            float dx = __fsub_rn(p[0], cx);
            float dy = __fsub_rn(p[1], cy);
            float dz = __fsub_rn(p[2], cz);
            rxv[r] = dx; ryv[r] = dy; rzv[r] = dz;
            // match numpy f32 ordering exactly: (dx*dx + dy*dy) + dz*dz, no FMA
            d2b[r] = __float_as_uint(__fadd_rn(__fadd_rn(__fmul_rn(dx, dx), __fmul_rn(dy, dy)), __fmul_rn(dz, dz)));
        }
    } else {
        #pragma unroll
        for (int r = 0; r < 8; ++r) {
            int j = r * 32 + l31;
            if (r == 7) j = min(j, NCAND - 1);
            int kh = (j * 205) >> 12;
            int kw = j - kh * 20;
            int ch = iclamp(h0 - 6 + kh, 0, HH - 1);
            int cw = iclamp(w0 - 10 + kw, 0, WW - 1);
            const float* p = base + (ch * WW + cw) * 3;
            float dx = __fsub_rn(p[0], cx);
            float dy = __fsub_rn(p[1], cy);
            float dz = __fsub_rn(p[2], cz);
            rxv[r] = dx; ryv[r] = dy; rzv[r] = dz;
            d2b[r] = __float_as_uint(__fadd_rn(__fadd_rn(__fmul_rn(dx, dx), __fmul_rn(dy, dy)), __fmul_rn(dz, dz)));
        }
    }
    if (l31 >= 16) d2b[7] = 0xFFFFFFFFu;   // j >= 240 invalid

    // ---- shared radix walk: build 32nd-smallest per half, latched early exit ----
    unsigned TA = 0, TB = 0;
    bool doneA = false, doneB = false;
    for (int bpos = 30; bpos >= 0; --bpos) {
        unsigned QA = doneA ? TA : (TA | (1u << bpos));
        unsigned QB = doneB ? TB : (TB | (1u << bpos));
        unsigned Qv = half ? QB : QA;     // one v_cndmask
        unsigned long long m0 = __ballot(d2b[0] < Qv);
        unsigned long long m1 = __ballot(d2b[1] < Qv);
        unsigned long long m2 = __ballot(d2b[2] < Qv);
        unsigned long long m3 = __ballot(d2b[3] < Qv);
        unsigned long long m4 = __ballot(d2b[4] < Qv);
        unsigned long long m5 = __ballot(d2b[5] < Qv);
        unsigned long long m6 = __ballot(d2b[6] < Qv);
        unsigned long long m7 = __ballot(d2b[7] < Qv);
        int cA = __popc((unsigned)m0) + __popc((unsigned)m1) + __popc((unsigned)m2) + __popc((unsigned)m3)
               + __popc((unsigned)m4) + __popc((unsigned)m5) + __popc((unsigned)m6) + __popc((unsigned)m7);
        int cB = __popc((unsigned)(m0 >> 32)) + __popc((unsigned)(m1 >> 32)) + __popc((unsigned)(m2 >> 32)) + __popc((unsigned)(m3 >> 32))
               + __popc((unsigned)(m4 >> 32)) + __popc((unsigned)(m5 >> 32)) + __popc((unsigned)(m6 >> 32)) + __popc((unsigned)(m7 >> 32));
        if (!doneA) { if (cA == 32) { TA = QA; doneA = true; } else if (cA < 32) TA = QA; }
        if (!doneB) { if (cB == 32) { TB = QB; doneB = true; } else if (cB < 32) TB = QB; }
        if (doneA && doneB) break;
    }
    // Exact-exit center: count(<T)==32 -> r=0 below, tie logic no-ops.
    // Full-walk center: T == 32nd smallest value, count(<T)<32, ties by lowest j.

    const unsigned Tv = half ? TB : TA;

    // strict-less counts per half -> tie quota r
    int cltA = 0, cltB = 0;
    #pragma unroll
    for (int r = 0; r < 8; ++r) {
        unsigned long long lm = __ballot(d2b[r] < Tv);
        cltA += __popc((unsigned)lm);
        cltB += __popc((unsigned)(lm >> 32));
    }
    const int rv = half ? (32 - cltB) : (32 - cltA);
    const unsigned hmLo = half ? 0u : 0xFFFFFFFFu;     // half-mask for mbcnt
    const unsigned hmHi = half ? 0xFFFFFFFFu : 0u;

    // ---- unified tie+scatter: rank winners, write rel-coords to LDS ----
    {
        int peA = 0, peB = 0, psA = 0, psB = 0;
        #pragma unroll
        for (int r = 0; r < 8; ++r) {
            bool eqr = (d2b[r] == Tv);
            unsigned long long em = __ballot(eqr);
            int pe = half ? peB : peA;
            bool tie = eqr && (pe + mbcnt2((unsigned)em & hmLo, (unsigned)(em >> 32) & hmHi) < rv);
            bool mine = (d2b[r] < Tv) || tie;
            unsigned long long sm = __ballot(mine);
            int ps = half ? psB : psA;
            int rank = ps + mbcnt2((unsigned)sm & hmLo, (unsigned)(sm >> 32) & hmHi);
            if (mine) selRel[wid * 64 + half * 32 + rank] = make_float4(rxv[r], ryv[r], rzv[r], 0.f);
            peA += __popc((unsigned)em);  peB += __popc((unsigned)(em >> 32));
            psA += __popc((unsigned)sm);  psB += __popc((unsigned)(sm >> 32));
        }
    }
    // same-wave LDS visibility: drain DS pipe, fence the scheduler
    asm volatile("s_waitcnt lgkmcnt(0)" ::: "memory");
    __builtin_amdgcn_sched_barrier(0);

    // ---- MLP: lane = half*32 + l31 processes neighbor l31 of its center; all 16 ch ----
    {
        float4 rel = selRel[wid * 64 + lane];
        v2f rx2 = (v2f){rel.x, rel.x};
        v2f ry2 = (v2f){rel.y, rel.y};
        v2f rz2 = (v2f){rel.z, rel.z};

        v2f a1[4];
        #pragma unroll
        for (int op = 0; op < 4; ++op) {
            v2f a = sB1p[op];
            a = __builtin_elementwise_fma(rx2, sW1p[0][op], a);
            a = __builtin_elementwise_fma(ry2, sW1p[1][op], a);
            a = __builtin_elementwise_fma(rz2, sW1p[2][op], a);
            a1[op] = __builtin_elementwise_max(a, (v2f)(0.f));
        }
        v2f a2[4];
        #pragma unroll
        for (int op = 0; op < 4; ++op) a2[op] = sB2p[op];
        #pragma unroll
        for (int i = 0; i < 8; ++i) {
            float h = a1[i >> 1][i & 1];
            v2f hb = (v2f){h, h};
            #pragma unroll
            for (int op = 0; op < 4; ++op)
                a2[op] = __builtin_elementwise_fma(hb, sW2p[i][op], a2[op]);
        }
        #pragma unroll
        for (int op = 0; op < 4; ++op) a2[op] = __builtin_elementwise_max(a2[op], (v2f)(0.f));

        v2f a3[8];
        #pragma unroll
        for (int op = 0; op < 8; ++op) a3[op] = sB3p[op];
        #pragma unroll
        for (int i = 0; i < 8; ++i) {
            float h = a2[i >> 1][i & 1];
            v2f hb = (v2f){h, h};
            #pragma unroll
            for (int op = 0; op < 8; ++op)
                a3[op] = __builtin_elementwise_fma(hb, sW3p[i][op], a3[op]);
        }

        // packed max-pool over 32 neighbor-lanes within each half
        // (xor<=16 never crosses the 32-lane halves); relu deferred past pool
        #pragma unroll
        for (int step = 16; step >= 1; step >>= 1) {
            #pragma unroll
            for (int op = 0; op < 8; ++op)
                a3[op] = __builtin_elementwise_max(a3[op], sxor(a3[op], step));
        }
        if (l31 == 0) {
            #pragma unroll
            for (int op = 0; op < 8; ++op)
                a3[op] = __builtin_elementwise_max(a3[op], (v2f)(0.f));
            float4* dst = (float4*)(out + ((size_t)(b * MM + m) * 32) + (size_t)cl * 16);
            dst[0] = make_float4(a3[0].x, a3[0].y, a3[1].x, a3[1].y);
            dst[1] = make_float4(a3[2].x, a3[2].y, a3[3].x, a3[3].y);
            dst[2] = make_float4(a3[4].x, a3[4].y, a3[5].x, a3[5].y);
            dst[3] = make_float4(a3[6].x, a3[6].y, a3[7].x, a3[7].y);
        }
    }
}

extern "C" void kernel_launch(void* const* d_in, const int* in_sizes, int n_in,
                              void* d_out, int out_size, void* d_ws, size_t ws_size,
                              hipStream_t stream) {
    const float* pos1 = (const float*)d_in[0];
    const float* pos2 = (const float*)d_in[1];
    const float* w1   = (const float*)d_in[2];
    const float* b1   = (const float*)d_in[3];
    const float* w2   = (const float*)d_in[4];
    const float* b2   = (const float*)d_in[5];
    const float* w3   = (const float*)d_in[6];
    const float* b3   = (const float*)d_in[7];
    float* out = (float*)d_out;

    dim3 grid(MM / 8, 4);   // 3328 blocks x {batch, cloud}; 2 centers/wave
    sa_fused<<<grid, 256, 0, stream>>>(pos1, pos2, w1, b1, w2, b2, w3, b3, out);
}

// Round 8
// 94.950 us; speedup vs baseline: 1.0984x; 1.0984x over previous
//
#include <hip/hip_runtime.h>
#include <hip/hip_bf16.h>

#define HH 256
#define WW 832
#define OHH 128
#define OWW 208
#define NCAND 240
#define MM (OHH*OWW)

typedef float v2f __attribute__((ext_vector_type(2)));

__device__ __forceinline__ int iclamp(int v, int lo, int hi) { return min(max(v, lo), hi); }
__device__ __forceinline__ int mbcnt2(unsigned long long m) {
    return __builtin_amdgcn_mbcnt_hi((unsigned)(m >> 32),
           __builtin_amdgcn_mbcnt_lo((unsigned)m, 0));
}
__device__ __forceinline__ v2f sxor(v2f v, int m) {
    v2f r; r.x = __shfl_xor(v.x, m); r.y = __shfl_xor(v.y, m); return r;
}

// 1 center/wave. Lane-major candidates: lane owns j = 4*lane+q (q=0..3), so
// kh = lane/5 is constant per lane and the 4 candidates are 12 contiguous
// floats of one window row -> 4 wide loads, no per-candidate address math.
// Lanes 60-63 hold exactly j>=240 (invalid) -> whole-lane invalidation.
__global__ void __launch_bounds__(256) sa_fused(
    const float* __restrict__ pos1, const float* __restrict__ pos2,
    const float* __restrict__ w1, const float* __restrict__ b1,
    const float* __restrict__ w2, const float* __restrict__ b2,
    const float* __restrict__ w3, const float* __restrict__ b3,
    float* __restrict__ out)
{
    // weights as channel-pair float2 for v_pk_fma_f32
    __shared__ v2f sW1p[3][4];
    __shared__ v2f sW2p[8][4];
    __shared__ v2f sW3p[8][8];
    __shared__ v2f sB1p[4], sB2p[4], sB3p[8];
    __shared__ float4 selRel[128];   // 4 waves x 32 selected rel-coords

    const int t = threadIdx.x;
    if (t < 12)              { int i = t >> 2,  op = t & 3;
        sW1p[i][op] = (v2f){w1[i*8 + 2*op], w1[i*8 + 2*op + 1]}; }
    if (t >= 16 && t < 48)   { int u = t - 16, i = u >> 2, op = u & 3;
        sW2p[i][op] = (v2f){w2[i*8 + 2*op], w2[i*8 + 2*op + 1]}; }
    if (t >= 64 && t < 128)  { int u = t - 64, i = u >> 3, op = u & 7;
        sW3p[i][op] = (v2f){w3[i*16 + 2*op], w3[i*16 + 2*op + 1]}; }
    if (t >= 128 && t < 132) { int u = t - 128; sB1p[u] = (v2f){b1[2*u], b1[2*u + 1]}; }
    if (t >= 132 && t < 136) { int u = t - 132; sB2p[u] = (v2f){b2[2*u], b2[2*u + 1]}; }
    if (t >= 136 && t < 144) { int u = t - 136; sB3p[u] = (v2f){b3[2*u], b3[2*u + 1]}; }
    __syncthreads();

    const int lane = t & 63;
    const int wid  = t >> 6;
    const int m    = blockIdx.x * 4 + wid;      // 0..26623
    const int b    = blockIdx.y & 1;
    const int cl   = blockIdx.y >> 1;
    const float* __restrict__ base = (cl ? pos2 : pos1) + (size_t)b * (HH * WW * 3);

    const unsigned um = (unsigned)m;
    const int oh = (int)(um / OWW);
    const int ow = (int)(um - (unsigned)oh * OWW);
    const int h0 = oh * 2, w0 = ow * 4;

    const float cx = base[(h0 * WW + w0) * 3 + 0];
    const float cy = base[(h0 * WW + w0) * 3 + 1];
    const float cz = base[(h0 * WW + w0) * 3 + 2];

    // lane -> window cell
    int kh  = (lane * 3277) >> 14;          // lane/5, exact for 0..63
    int kwb = (lane - kh * 5) * 4;
    if (lane >= 60) { kh = 11; kwb = 0; }   // tail: safe dummy cell (invalidated below)

    unsigned d2b[4];
    float rxv[4], ryv[4], rzv[4];
    const bool interior = ((unsigned)(oh - 3) <= 122u) && ((unsigned)(ow - 3) <= 202u);
    if (interior) {
        // 12 contiguous floats = 4 points; float-index ≡ 2 (mod 4) for all blocks
        // -> float2 / float4(+2) / float4(+6) / float2(+10) all naturally aligned.
        const float* p = base + ((h0 - 6 + kh) * WW + (w0 - 10 + kwb)) * 3;
        float2 Av = *(const float2*)(p);
        float4 Bv = *(const float4*)(p + 2);
        float4 Cv = *(const float4*)(p + 6);
        float2 Dv = *(const float2*)(p + 10);
        float px[4] = {Av.x, Bv.y, Cv.x, Cv.w};
        float py[4] = {Av.y, Bv.z, Cv.y, Dv.x};
        float pz[4] = {Bv.x, Bv.w, Cv.z, Dv.y};
        #pragma unroll
        for (int q = 0; q < 4; ++q) {
            float dx = __fsub_rn(px[q], cx);
            float dy = __fsub_rn(py[q], cy);
            float dz = __fsub_rn(pz[q], cz);
            rxv[q] = dx; ryv[q] = dy; rzv[q] = dz;
            // match numpy f32 ordering exactly: (dx*dx + dy*dy) + dz*dz, no FMA
            d2b[q] = __float_as_uint(__fadd_rn(__fadd_rn(__fmul_rn(dx, dx), __fmul_rn(dy, dy)), __fmul_rn(dz, dz)));
        }
    } else {
        int chh = iclamp(h0 - 6 + kh, 0, HH - 1);   // kh constant per lane: one clamp
        #pragma unroll
        for (int q = 0; q < 4; ++q) {
            int cw = iclamp(w0 - 10 + kwb + q, 0, WW - 1);
            const float* p = base + (chh * WW + cw) * 3;
            float dx = __fsub_rn(p[0], cx);
            float dy = __fsub_rn(p[1], cy);
            float dz = __fsub_rn(p[2], cz);
            rxv[q] = dx; ryv[q] = dy; rzv[q] = dz;
            d2b[q] = __float_as_uint(__fadd_rn(__fadd_rn(__fmul_rn(dx, dx), __fmul_rn(dy, dy)), __fmul_rn(dz, dz)));
        }
    }
    if (lane >= 60) { d2b[0] = d2b[1] = d2b[2] = d2b[3] = 0xFFFFFFFFu; }

    // ---- radix-select the 32nd-smallest d2; track c0 = count(<T) in-walk ----
    unsigned T = 0; int c0 = 0; bool exact = false;
    for (int bpos = 30; bpos >= 0; --bpos) {
        unsigned Q = T | (1u << bpos);
        unsigned long long t0 = __ballot(d2b[0] < Q);
        unsigned long long t1 = __ballot(d2b[1] < Q);
        unsigned long long t2 = __ballot(d2b[2] < Q);
        unsigned long long t3 = __ballot(d2b[3] < Q);
        int c = __popcll(t0) + __popcll(t1) + __popcll(t2) + __popcll(t3);
        if (c == 32) { T = Q; c0 = 32; exact = true; break; }   // {d2<T} is the answer set
        if (c < 32)  { T = Q; c0 = c; }
    }

    // ---- ties at T, ranked in GLOBAL candidate-index order (j = 4*lane+q) ----
    bool tie0 = false, tie1 = false, tie2 = false, tie3 = false;
    if (!exact) {
        const int r = 32 - c0;            // quota; T == exact 32nd smallest value
        bool eq0 = (d2b[0] == T), eq1 = (d2b[1] == T), eq2 = (d2b[2] == T), eq3 = (d2b[3] == T);
        unsigned long long e0 = __ballot(eq0);
        unsigned long long e1 = __ballot(eq1);
        unsigned long long e2 = __ballot(eq2);
        unsigned long long e3 = __ballot(eq3);
        // rank(q) = #ties with smaller j = sum_q' mbcnt(e_q') + sum_{q'<q} eq_q'
        int SA = mbcnt2(e0) + mbcnt2(e1) + mbcnt2(e2) + mbcnt2(e3);
        int E1 = (int)eq0, E2 = E1 + (int)eq1, E3 = E2 + (int)eq2;
        tie0 = eq0 && (SA      < r);
        tie1 = eq1 && (SA + E1 < r);
        tie2 = eq2 && (SA + E2 < r);
        tie3 = eq3 && (SA + E3 < r);
    }

    // ---- scatter the 32 winners' rel-coords to selRel[wid][rank] ----
    {
        bool m0 = (d2b[0] < T) || tie0;
        bool m1 = (d2b[1] < T) || tie1;
        bool m2 = (d2b[2] < T) || tie2;
        bool m3 = (d2b[3] < T) || tie3;
        unsigned long long s0 = __ballot(m0);
        unsigned long long s1 = __ballot(m1);
        unsigned long long s2 = __ballot(m2);
        unsigned long long s3 = __ballot(m3);
        int p1 = __popcll(s0);
        int p2 = p1 + __popcll(s1);
        int p3 = p2 + __popcll(s2);
        int lb = wid * 32;
        if (m0) selRel[lb +      mbcnt2(s0)] = make_float4(rxv[0], ryv[0], rzv[0], 0.f);
        if (m1) selRel[lb + p1 + mbcnt2(s1)] = make_float4(rxv[1], ryv[1], rzv[1], 0.f);
        if (m2) selRel[lb + p2 + mbcnt2(s2)] = make_float4(rxv[2], ryv[2], rzv[2], 0.f);
        if (m3) selRel[lb + p3 + mbcnt2(s3)] = make_float4(rxv[3], ryv[3], rzv[3], 0.f);
    }
    // same-wave LDS visibility: drain DS pipe, fence the scheduler
    asm volatile("s_waitcnt lgkmcnt(0)" ::: "memory");
    __builtin_amdgcn_sched_barrier(0);

    // ---- MLP: lane l and l+32 process neighbor (l&31); halves split layer-3 channels ----
    {
        float4 rel = selRel[wid * 32 + (lane & 31)];
        v2f rx2 = (v2f){rel.x, rel.x};
        v2f ry2 = (v2f){rel.y, rel.y};
        v2f rz2 = (v2f){rel.z, rel.z};

        v2f a1[4];
        #pragma unroll
        for (int op = 0; op < 4; ++op) {
            v2f a = sB1p[op];
            a = __builtin_elementwise_fma(rx2, sW1p[0][op], a);
            a = __builtin_elementwise_fma(ry2, sW1p[1][op], a);
            a = __builtin_elementwise_fma(rz2, sW1p[2][op], a);
            a1[op] = __builtin_elementwise_max(a, (v2f)(0.f));
        }
        v2f a2[4];
        #pragma unroll
        for (int op = 0; op < 4; ++op) a2[op] = sB2p[op];
        #pragma unroll
        for (int i = 0; i < 8; ++i) {
            float h = a1[i >> 1][i & 1];
            v2f hb = (v2f){h, h};
            #pragma unroll
            for (int op = 0; op < 4; ++op)
                a2[op] = __builtin_elementwise_fma(hb, sW2p[i][op], a2[op]);
        }
        #pragma unroll
        for (int op = 0; op < 4; ++op) a2[op] = __builtin_elementwise_max(a2[op], (v2f)(0.f));

        const int obp = (lane >> 5) << 2;   // lanes 0-31: ch 0-7; lanes 32-63: ch 8-15
        v2f a3[4];
        #pragma unroll
        for (int op = 0; op < 4; ++op) a3[op] = sB3p[obp + op];
        #pragma unroll
        for (int i = 0; i < 8; ++i) {
            float h = a2[i >> 1][i & 1];
            v2f hb = (v2f){h, h};
            #pragma unroll
            for (int op = 0; op < 4; ++op)
                a3[op] = __builtin_elementwise_fma(hb, sW3p[i][obp + op], a3[op]);
        }

        // packed max-pool over the 32 neighbor-lanes within each half
        // (xor<=16 never crosses the 32-lane halves); relu deferred past pool
        #pragma unroll
        for (int step = 16; step >= 1; step >>= 1) {
            #pragma unroll
            for (int op = 0; op < 4; ++op)
                a3[op] = __builtin_elementwise_max(a3[op], sxor(a3[op], step));
        }
        if ((lane & 31) == 0) {
            #pragma unroll
            for (int op = 0; op < 4; ++op)
                a3[op] = __builtin_elementwise_max(a3[op], (v2f)(0.f));
            const int ob = (lane >> 5) << 3;
            float4* dst = (float4*)(out + ((size_t)(b * MM + m) * 32) + (size_t)cl * 16 + ob);
            dst[0] = make_float4(a3[0].x, a3[0].y, a3[1].x, a3[1].y);
            dst[1] = make_float4(a3[2].x, a3[2].y, a3[3].x, a3[3].y);
        }
    }
}

extern "C" void kernel_launch(void* const* d_in, const int* in_sizes, int n_in,
                              void* d_out, int out_size, void* d_ws, size_t ws_size,
                              hipStream_t stream) {
    const float* pos1 = (const float*)d_in[0];
    const float* pos2 = (const float*)d_in[1];
    const float* w1   = (const float*)d_in[2];
    const float* b1   = (const float*)d_in[3];
    const float* w2   = (const float*)d_in[4];
    const float* b2   = (const float*)d_in[5];
    const float* w3   = (const float*)d_in[6];
    const float* b3   = (const float*)d_in[7];
    float* out = (float*)d_out;

    dim3 grid(MM / 4, 4);   // 6656 blocks x {batch, cloud}; 1 center/wave
    sa_fused<<<grid, 256, 0, stream>>>(pos1, pos2, w1, b1, w2, b2, w3, b3, out);
}

// Round 9
// 88.449 us; speedup vs baseline: 1.1791x; 1.0735x over previous
//
#include <hip/hip_runtime.h>
#include <hip/hip_bf16.h>

#define HH 256
#define WW 832
#define OHH 128
#define OWW 208
#define NCAND 240
#define MM (OHH*OWW)

typedef float v2f __attribute__((ext_vector_type(2)));

__device__ __forceinline__ int iclamp(int v, int lo, int hi) { return min(max(v, lo), hi); }
__device__ __forceinline__ int mbcnt2(unsigned long long m) {
    return __builtin_amdgcn_mbcnt_hi((unsigned)(m >> 32),
           __builtin_amdgcn_mbcnt_lo((unsigned)m, 0));
}
__device__ __forceinline__ v2f sxor(v2f v, int m) {
    v2f r; r.x = __shfl_xor(v.x, m); r.y = __shfl_xor(v.y, m); return r;
}
__device__ __forceinline__ v2f lo2(float4 f) { return (v2f){f.x, f.y}; }
__device__ __forceinline__ v2f hi2(float4 f) { return (v2f){f.z, f.w}; }

// One wave = 2 consecutive centers, processed SEQUENTIALLY through
// distance/select (full 64-lane parallelism, R8 memory pattern preserved),
// then ONE shared MLP+pool pass: lanes 0-31 = center A's 32 neighbors,
// lanes 32-63 = center B's. Weight reads + MLP overhead amortize 2x.
__global__ void __launch_bounds__(256) sa_fused(
    const float* __restrict__ pos1, const float* __restrict__ pos2,
    const float* __restrict__ w1, const float* __restrict__ b1,
    const float* __restrict__ w2, const float* __restrict__ b2,
    const float* __restrict__ w3, const float* __restrict__ b3,
    float* __restrict__ out)
{
    // weights as channel-quad float4 (one b128 read = two v2f pk_fma operands)
    __shared__ float4 sW1q[3][2];
    __shared__ float4 sW2q[8][2];
    __shared__ float4 sW3q[8][4];
    __shared__ float4 sB1q[2], sB2q[2], sB3q[4];
    __shared__ float4 selRel[256];   // 4 waves x 2 centers x 32 rel-coords

    const int t = threadIdx.x;
    if (t < 6)            { int i = t >> 1, qd = (t & 1) * 4;
        sW1q[i][t & 1] = make_float4(w1[i*8+qd], w1[i*8+qd+1], w1[i*8+qd+2], w1[i*8+qd+3]); }
    if (t >= 8 && t < 24) { int u = t - 8, i = u >> 1, qd = (u & 1) * 4;
        sW2q[i][u & 1] = make_float4(w2[i*8+qd], w2[i*8+qd+1], w2[i*8+qd+2], w2[i*8+qd+3]); }
    if (t >= 32 && t < 64){ int u = t - 32, i = u >> 2, qd = (u & 3) * 4;
        sW3q[i][u & 3] = make_float4(w3[i*16+qd], w3[i*16+qd+1], w3[i*16+qd+2], w3[i*16+qd+3]); }
    if (t >= 64 && t < 66){ int u = (t - 64) * 4; sB1q[t-64] = make_float4(b1[u], b1[u+1], b1[u+2], b1[u+3]); }
    if (t >= 66 && t < 68){ int u = (t - 66) * 4; sB2q[t-66] = make_float4(b2[u], b2[u+1], b2[u+2], b2[u+3]); }
    if (t >= 68 && t < 72){ int u = (t - 68) * 4; sB3q[t-68] = make_float4(b3[u], b3[u+1], b3[u+2], b3[u+3]); }
    __syncthreads();

    const int lane = t & 63;
    const int wid  = t >> 6;
    const int l31  = lane & 31;
    const int mA   = blockIdx.x * 8 + wid * 2;   // centers mA, mA+1
    const int b    = blockIdx.y & 1;
    const int cl   = blockIdx.y >> 1;
    const float* __restrict__ base = (cl ? pos2 : pos1) + (size_t)b * (HH * WW * 3);

    // lane -> window cell (lane-major: j = 4*lane+q; kh const per lane)
    int kh  = (lane * 3277) >> 14;          // lane/5, exact for 0..63
    int kwb = (lane - kh * 5) * 4;
    if (lane >= 60) { kh = 11; kwb = 0; }   // tail: safe dummy cell (invalidated)

    #pragma unroll
    for (int cc = 0; cc < 2; ++cc) {
        const int m  = mA + cc;
        const int oh = (int)(((unsigned)(m >> 4) * 5042u) >> 16);  // m/208, exact
        const int ow = m - oh * OWW;
        const int h0 = oh * 2, w0 = ow * 4;

        const float cx = base[(h0 * WW + w0) * 3 + 0];
        const float cy = base[(h0 * WW + w0) * 3 + 1];
        const float cz = base[(h0 * WW + w0) * 3 + 2];

        unsigned d2b[4];
        float rxv[4], ryv[4], rzv[4];
        const bool interior = ((unsigned)(oh - 3) <= 122u) && ((unsigned)(ow - 3) <= 202u);
        if (interior) {
            // 12 contiguous floats; float-index ≡ 2 (mod 4) -> all naturally aligned
            const float* p = base + ((h0 - 6 + kh) * WW + (w0 - 10 + kwb)) * 3;
            float2 Av = *(const float2*)(p);
            float4 Bv = *(const float4*)(p + 2);
            float4 Cv = *(const float4*)(p + 6);
            float2 Dv = *(const float2*)(p + 10);
            float px[4] = {Av.x, Bv.y, Cv.x, Cv.w};
            float py[4] = {Av.y, Bv.z, Cv.y, Dv.x};
            float pz[4] = {Bv.x, Bv.w, Cv.z, Dv.y};
            #pragma unroll
            for (int q = 0; q < 4; ++q) {
                float dx = __fsub_rn(px[q], cx);
                float dy = __fsub_rn(py[q], cy);
                float dz = __fsub_rn(pz[q], cz);
                rxv[q] = dx; ryv[q] = dy; rzv[q] = dz;
                // match numpy f32 ordering exactly: (dx*dx + dy*dy) + dz*dz, no FMA
                d2b[q] = __float_as_uint(__fadd_rn(__fadd_rn(__fmul_rn(dx, dx), __fmul_rn(dy, dy)), __fmul_rn(dz, dz)));
            }
        } else {
            int chh = iclamp(h0 - 6 + kh, 0, HH - 1);
            #pragma unroll
            for (int q = 0; q < 4; ++q) {
                int cw = iclamp(w0 - 10 + kwb + q, 0, WW - 1);
                const float* p = base + (chh * WW + cw) * 3;
                float dx = __fsub_rn(p[0], cx);
                float dy = __fsub_rn(p[1], cy);
                float dz = __fsub_rn(p[2], cz);
                rxv[q] = dx; ryv[q] = dy; rzv[q] = dz;
                d2b[q] = __float_as_uint(__fadd_rn(__fadd_rn(__fmul_rn(dx, dx), __fmul_rn(dy, dy)), __fmul_rn(dz, dz)));
            }
        }
        if (lane >= 60) { d2b[0] = d2b[1] = d2b[2] = d2b[3] = 0xFFFFFFFFu; }

        // ---- radix-select 32nd-smallest; save exit ballots on exact hit ----
        unsigned T = 0; int c0 = 0; bool exact = false;
        unsigned long long sv0 = 0, sv1 = 0, sv2 = 0, sv3 = 0;
        for (int bpos = 30; bpos >= 0; --bpos) {
            unsigned Q = T | (1u << bpos);
            unsigned long long t0 = __ballot(d2b[0] < Q);
            unsigned long long t1 = __ballot(d2b[1] < Q);
            unsigned long long t2 = __ballot(d2b[2] < Q);
            unsigned long long t3 = __ballot(d2b[3] < Q);
            int c = __popcll(t0) + __popcll(t1) + __popcll(t2) + __popcll(t3);
            if (c == 32) { T = Q; exact = true; sv0 = t0; sv1 = t1; sv2 = t2; sv3 = t3; break; }
            if (c < 32)  { T = Q; c0 = c; }
        }

        bool m0, m1, m2, m3;
        unsigned long long s0, s1, s2, s3;
        if (exact) {
            // {d2 < T} is exactly the answer set; ballots already in hand
            m0 = (d2b[0] < T); m1 = (d2b[1] < T); m2 = (d2b[2] < T); m3 = (d2b[3] < T);
            s0 = sv0; s1 = sv1; s2 = sv2; s3 = sv3;
        } else {
            // T == exact 32nd-smallest value; ties ranked in global j order
            const int r = 32 - c0;
            bool eq0 = (d2b[0] == T), eq1 = (d2b[1] == T), eq2 = (d2b[2] == T), eq3 = (d2b[3] == T);
            unsigned long long e0 = __ballot(eq0);
            unsigned long long e1 = __ballot(eq1);
            unsigned long long e2 = __ballot(eq2);
            unsigned long long e3 = __ballot(eq3);
            int SA = mbcnt2(e0) + mbcnt2(e1) + mbcnt2(e2) + mbcnt2(e3);
            int E1 = (int)eq0, E2 = E1 + (int)eq1, E3 = E2 + (int)eq2;
            m0 = (d2b[0] < T) || (eq0 && (SA      < r));
            m1 = (d2b[1] < T) || (eq1 && (SA + E1 < r));
            m2 = (d2b[2] < T) || (eq2 && (SA + E2 < r));
            m3 = (d2b[3] < T) || (eq3 && (SA + E3 < r));
            s0 = __ballot(m0); s1 = __ballot(m1); s2 = __ballot(m2); s3 = __ballot(m3);
        }

        // ---- scatter winners' rel-coords to selRel[wid][cc][rank] ----
        {
            int p1 = __popcll(s0);
            int p2 = p1 + __popcll(s1);
            int p3 = p2 + __popcll(s2);
            int lb = wid * 64 + cc * 32;
            if (m0) selRel[lb +      mbcnt2(s0)] = make_float4(rxv[0], ryv[0], rzv[0], 0.f);
            if (m1) selRel[lb + p1 + mbcnt2(s1)] = make_float4(rxv[1], ryv[1], rzv[1], 0.f);
            if (m2) selRel[lb + p2 + mbcnt2(s2)] = make_float4(rxv[2], ryv[2], rzv[2], 0.f);
            if (m3) selRel[lb + p3 + mbcnt2(s3)] = make_float4(rxv[3], ryv[3], rzv[3], 0.f);
        }
    }
    // same-wave LDS visibility: drain DS pipe, fence the scheduler
    asm volatile("s_waitcnt lgkmcnt(0)" ::: "memory");
    __builtin_amdgcn_sched_barrier(0);

    // ---- MLP: lane = half*32 + n processes neighbor n of center mA+half; all 16 ch ----
    {
        float4 rel = selRel[wid * 64 + lane];
        v2f rx2 = (v2f){rel.x, rel.x};
        v2f ry2 = (v2f){rel.y, rel.y};
        v2f rz2 = (v2f){rel.z, rel.z};

        v2f a1[4];
        {
            float4 bq0 = sB1q[0], bq1 = sB1q[1];
            float4 x0 = sW1q[0][0], x1 = sW1q[0][1];
            float4 y0 = sW1q[1][0], y1 = sW1q[1][1];
            float4 z0 = sW1q[2][0], z1 = sW1q[2][1];
            a1[0] = __builtin_elementwise_fma(rx2, lo2(x0), lo2(bq0));
            a1[1] = __builtin_elementwise_fma(rx2, hi2(x0), hi2(bq0));
            a1[2] = __builtin_elementwise_fma(rx2, lo2(x1), lo2(bq1));
            a1[3] = __builtin_elementwise_fma(rx2, hi2(x1), hi2(bq1));
            a1[0] = __builtin_elementwise_fma(ry2, lo2(y0), a1[0]);
            a1[1] = __builtin_elementwise_fma(ry2, hi2(y0), a1[1]);
            a1[2] = __builtin_elementwise_fma(ry2, lo2(y1), a1[2]);
            a1[3] = __builtin_elementwise_fma(ry2, hi2(y1), a1[3]);
            a1[0] = __builtin_elementwise_fma(rz2, lo2(z0), a1[0]);
            a1[1] = __builtin_elementwise_fma(rz2, hi2(z0), a1[1]);
            a1[2] = __builtin_elementwise_fma(rz2, lo2(z1), a1[2]);
            a1[3] = __builtin_elementwise_fma(rz2, hi2(z1), a1[3]);
            #pragma unroll
            for (int op = 0; op < 4; ++op) a1[op] = __builtin_elementwise_max(a1[op], (v2f)(0.f));
        }
        v2f a2[4] = {lo2(sB2q[0]), hi2(sB2q[0]), lo2(sB2q[1]), hi2(sB2q[1])};
        #pragma unroll
        for (int i = 0; i < 8; ++i) {
            float h = a1[i >> 1][i & 1];
            v2f hb = (v2f){h, h};
            float4 wl = sW2q[i][0], wh = sW2q[i][1];
            a2[0] = __builtin_elementwise_fma(hb, lo2(wl), a2[0]);
            a2[1] = __builtin_elementwise_fma(hb, hi2(wl), a2[1]);
            a2[2] = __builtin_elementwise_fma(hb, lo2(wh), a2[2]);
            a2[3] = __builtin_elementwise_fma(hb, hi2(wh), a2[3]);
        }
        #pragma unroll
        for (int op = 0; op < 4; ++op) a2[op] = __builtin_elementwise_max(a2[op], (v2f)(0.f));

        v2f a3[8] = {lo2(sB3q[0]), hi2(sB3q[0]), lo2(sB3q[1]), hi2(sB3q[1]),
                     lo2(sB3q[2]), hi2(sB3q[2]), lo2(sB3q[3]), hi2(sB3q[3])};
        #pragma unroll
        for (int i = 0; i < 8; ++i) {
            float h = a2[i >> 1][i & 1];
            v2f hb = (v2f){h, h};
            float4 q0 = sW3q[i][0], q1 = sW3q[i][1], q2 = sW3q[i][2], q3 = sW3q[i][3];
            a3[0] = __builtin_elementwise_fma(hb, lo2(q0), a3[0]);
            a3[1] = __builtin_elementwise_fma(hb, hi2(q0), a3[1]);
            a3[2] = __builtin_elementwise_fma(hb, lo2(q1), a3[2]);
            a3[3] = __builtin_elementwise_fma(hb, hi2(q1), a3[3]);
            a3[4] = __builtin_elementwise_fma(hb, lo2(q2), a3[4]);
            a3[5] = __builtin_elementwise_fma(hb, hi2(q2), a3[5]);
            a3[6] = __builtin_elementwise_fma(hb, lo2(q3), a3[6]);
            a3[7] = __builtin_elementwise_fma(hb, hi2(q3), a3[7]);
        }

        // packed max-pool within each 32-lane half (one center per half);
        // relu deferred past pool (relu(max)=max(relu))
        #pragma unroll
        for (int step = 16; step >= 1; step >>= 1) {
            #pragma unroll
            for (int op = 0; op < 8; ++op)
                a3[op] = __builtin_elementwise_max(a3[op], sxor(a3[op], step));
        }
        if (l31 == 0) {
            #pragma unroll
            for (int op = 0; op < 8; ++op)
                a3[op] = __builtin_elementwise_max(a3[op], (v2f)(0.f));
            const int ms = mA + (lane >> 5);
            float4* dst = (float4*)(out + ((size_t)(b * MM + ms) * 32) + (size_t)cl * 16);
            dst[0] = make_float4(a3[0].x, a3[0].y, a3[1].x, a3[1].y);
            dst[1] = make_float4(a3[2].x, a3[2].y, a3[3].x, a3[3].y);
            dst[2] = make_float4(a3[4].x, a3[4].y, a3[5].x, a3[5].y);
            dst[3] = make_float4(a3[6].x, a3[6].y, a3[7].x, a3[7].y);
        }
    }
}

extern "C" void kernel_launch(void* const* d_in, const int* in_sizes, int n_in,
                              void* d_out, int out_size, void* d_ws, size_t ws_size,
                              hipStream_t stream) {
    const float* pos1 = (const float*)d_in[0];
    const float* pos2 = (const float*)d_in[1];
    const float* w1   = (const float*)d_in[2];
    const float* b1   = (const float*)d_in[3];
    const float* w2   = (const float*)d_in[4];
    const float* b2   = (const float*)d_in[5];
    const float* w3   = (const float*)d_in[6];
    const float* b3   = (const float*)d_in[7];
    float* out = (float*)d_out;

    dim3 grid(MM / 8, 4);   // 3328 blocks x {batch, cloud}; 2 centers/wave (sequential)
    sa_fused<<<grid, 256, 0, stream>>>(pos1, pos2, w1, b1, w2, b2, w3, b3, out);
}